// Round 3
// baseline (535.637 us; speedup 1.0000x reference)
//
#include <hip/hip_runtime.h>
#include <math.h>

// GIN: N=100000 nodes, E=1600000 edges, F=D=64, L=3 layers, C=10 classes.
// R16: (a) revert R15's per-lane gather (regressed: scalar-index row
//   broadcast is cheaper); agg kernels now use masked fixed-width rounds:
//   deg<=16 -> 1x16 masked slots, deg<=32 -> 2x16 back-to-back (one
//   latency exposure), loop only for deg>32. Kills the serial 4-wide tail
//   that dominated the latency-bound critical path.
//   (b) k_head_final3 -> k_head_mfma: JK heads on MFMA (fcW hi/lo bf16 in
//   LDS, BN+ReLU on A in-register, acc accumulated across 3 layers),
//   log_softmax via 16-lane-group shfl butterflies. Was ~45us VALU-bound
//   (1920 scalar FMA/thread); now memory-bound ~13us.
//   R14 MFMA k_gemm2 and CSR build unchanged.

#define BN_EPS 1e-5f
#define NBKT 256     // dst buckets (dst>>9)
#define BCAP 12288   // per-bucket edge capacity (mean 8163, +45 sigma)
#define PCHUNK 4096  // edges per partition block

typedef __attribute__((ext_vector_type(8))) short bf16x8;
typedef __attribute__((ext_vector_type(4))) float f32x4;

__device__ __forceinline__ float bf2f(unsigned short u) {
  return __uint_as_float(((unsigned int)u) << 16);
}
__device__ __forceinline__ unsigned short f2bf(float x) {  // RNE
  unsigned int b = __float_as_uint(x);
  return (unsigned short)((b + 0x7FFFu + ((b >> 16) & 1u)) >> 16);
}

// ---------- CSR build ----------

// combined dispatch: blocks [0,nparts) partition edges into fixed-capacity
// dst-buckets (direct atomicAdd on bcur); rest do head_init (+x16 shadow).
__global__ __launch_bounds__(256) void k_part_head(
    const int* __restrict__ src, const int* __restrict__ dst,
    int* __restrict__ bcur, int2* __restrict__ ep, int E, int nparts,
    const float* __restrict__ x, const float* __restrict__ fcW0,
    const float* __restrict__ fcb, float* __restrict__ logits,
    unsigned short* __restrict__ x16, int N) {
  __shared__ char smem[256 * 17 * 4];
  int tid = threadIdx.x;
  if ((int)blockIdx.x < nparts) {
    int* lh = (int*)smem;
    int* lbase = lh + NBKT;
    int* lcur = lh + 2 * NBKT;
    int base = blockIdx.x * PCHUNK;
    int end = min(base + PCHUNK, E);
    lh[tid] = 0;
    lcur[tid] = 0;
    __syncthreads();
    for (int e = base + tid; e < end; e += 256) atomicAdd(&lh[dst[e] >> 9], 1);
    __syncthreads();
    int c = lh[tid];
    lbase[tid] = c ? (tid * BCAP + atomicAdd(&bcur[tid], c)) : 0;
    __syncthreads();
    for (int e = base + tid; e < end; e += 256) {
      int d = dst[e];
      int b = d >> 9;
      int r = atomicAdd(&lcur[b], 1);
      ep[lbase[b] + r] = make_int2(src[e], d);
    }
  } else {
    float* vs = (float*)smem;
    int n0 = (blockIdx.x - nparts) * 256;
    int n = n0 + tid;
    float acc[10];
#pragma unroll
    for (int c = 0; c < 10; c++) acc[c] = 0.f;
#pragma unroll 1
    for (int fb = 0; fb < 64; fb += 16) {
      __syncthreads();
#pragma unroll
      for (int g = 0; g < 4; g++) {
        int r = g * 64 + (tid >> 2);
        int q = tid & 3;
        int rn = n0 + r;
        float4 t = make_float4(0.f, 0.f, 0.f, 0.f);
        if (rn < N) {
          t = *(const float4*)(x + (size_t)rn * 64 + fb + 4 * q);
          *(ushort4*)(x16 + (size_t)rn * 64 + fb + 4 * q) =
              make_ushort4(f2bf(t.x), f2bf(t.y), f2bf(t.z), f2bf(t.w));
        }
        int base = r * 17 + 4 * q;
        vs[base] = t.x;
        vs[base + 1] = t.y;
        vs[base + 2] = t.z;
        vs[base + 3] = t.w;
      }
      __syncthreads();
      for (int fc = 0; fc < 16; fc++) {
        int f = fb + fc;
        float vf = vs[tid * 17 + fc];
        const float* wr = fcW0 + f * 10;
#pragma unroll
        for (int c = 0; c < 10; c++) acc[c] += vf * wr[c];
      }
    }
    if (n < N) {
      float* lr = logits + (size_t)n * 10;
#pragma unroll
      for (int c = 0; c < 10; c++)
        lr[c] = acc[c] + (fcb[c] + fcb[10 + c] + fcb[20 + c] + fcb[30 + c]);
    }
  }
}

// per-bucket LDS counting sort. Emits offs, bend[b], csr. Blk 0 zeroes stats.
__global__ __launch_bounds__(256) void k_bucketsort(
    const int2* __restrict__ ep, const int* __restrict__ bcur,
    int* __restrict__ offs, int* __restrict__ bend, int* __restrict__ csr,
    float* __restrict__ stats) {
  __shared__ int cnt[512];
  __shared__ int ts[256];
  __shared__ int cur[512];
  int t = threadIdx.x;
  int b = blockIdx.x;
  if (b == 0) {
    for (int i = t; i < 768; i += 256) stats[i] = 0.f;
  }
  int lo = b * BCAP;
  int hi = lo + bcur[b];
  cnt[t] = 0;
  cnt[t + 256] = 0;
  __syncthreads();
  for (int e = lo + t; e < hi; e += 256) atomicAdd(&cnt[ep[e].y & 511], 1);
  __syncthreads();
  int c0 = cnt[2 * t], c1 = cnt[2 * t + 1];
  int s = c0 + c1;
  ts[t] = s;
  __syncthreads();
  for (int o = 1; o < 256; o <<= 1) {
    int add = (t >= o) ? ts[t - o] : 0;
    __syncthreads();
    ts[t] += add;
    __syncthreads();
  }
  int excl = ts[t] - s;
  cur[2 * t] = excl;
  cur[2 * t + 1] = excl + c0;
  int n0 = b << 9;
  offs[n0 + 2 * t] = lo + excl;
  offs[n0 + 2 * t + 1] = lo + excl + c0;
  if (t == 255) bend[b] = lo + ts[255];
  __syncthreads();
  for (int e = lo + t; e < hi; e += 256) {
    int2 p = ep[e];
    int pos = atomicAdd(&cur[p.y & 511], 1);
    csr[lo + pos] = p.x;
  }
}

// ---------- compute ----------

// layer-0 aggregation: v16[n] = bf16(x16[n] + sum x16[src])
// wave = 1 node, lane = feature. Masked fixed-width rounds: all loads of a
// round are independent (scalar clamped idx) -> one latency exposure.
__global__ __launch_bounds__(256) void k_agg(
    const unsigned short* __restrict__ h16, const int* __restrict__ offs,
    const int* __restrict__ bend, const int* __restrict__ csr,
    unsigned short* __restrict__ vout, int N) {
  int gid = blockIdx.x * blockDim.x + threadIdx.x;
  int wid = __builtin_amdgcn_readfirstlane(gid >> 6);
  int lane = threadIdx.x & 63;
  if (wid >= N) return;
  int e0 = offs[wid];
  int e1 = ((wid & 511) == 511) ? bend[wid >> 9] : offs[wid + 1];
  float acc = bf2f(h16[(size_t)wid * 64 + lane]);
  int deg = e1 - e0;
  if (deg > 0) {
    int last = e1 - 1;
    if (deg <= 16) {
#pragma unroll
      for (int i = 0; i < 16; i++) {
        int m = e0 + i;
        int s = csr[min(m, last)];
        float v = bf2f(h16[(size_t)s * 64 + lane]);
        acc += (m < e1) ? v : 0.f;
      }
    } else {
#pragma unroll
      for (int i = 0; i < 32; i++) {
        int m = e0 + i;
        int s = csr[min(m, last)];
        float v = bf2f(h16[(size_t)s * 64 + lane]);
        acc += (m < e1) ? v : 0.f;
      }
      for (int e = e0 + 32; e < e1; e += 16) {
#pragma unroll
        for (int i = 0; i < 16; i++) {
          int m = e + i;
          int s = csr[min(m, last)];
          float v = bf2f(h16[(size_t)s * 64 + lane]);
          acc += (m < e1) ? v : 0.f;
        }
      }
    }
  }
  vout[(size_t)wid * 64 + lane] = f2bf(acc);
}

// BN+ReLU aggregation: v16[n] = bf16(relu(z16[n]*A+B) + sum relu(z16[src]*A+B))
__global__ __launch_bounds__(256) void k_aggbn(
    const unsigned short* __restrict__ z16,
    const float* __restrict__ stats_in, const float* __restrict__ gv,
    const float* __restrict__ bev,
    const int* __restrict__ offs, const int* __restrict__ bend,
    const int* __restrict__ csr, unsigned short* __restrict__ vout, int N) {
  __shared__ float ABs[128];
  int tid = threadIdx.x;
  if (tid < 64) {
    float inv_n = 1.f / (float)N;
    float mu = stats_in[tid] * inv_n;
    float var = stats_in[64 + tid] * inv_n - mu * mu;
    float A = rsqrtf(var + BN_EPS) * gv[tid];
    ABs[tid] = A;
    ABs[64 + tid] = bev[tid] - mu * A;
  }
  __syncthreads();
  int gid = blockIdx.x * blockDim.x + tid;
  int wid = __builtin_amdgcn_readfirstlane(gid >> 6);
  int lane = tid & 63;
  if (wid >= N) return;
  float A = ABs[lane], B = ABs[64 + lane];
  int e0 = offs[wid];
  int e1 = ((wid & 511) == 511) ? bend[wid >> 9] : offs[wid + 1];
  float acc = fmaxf(bf2f(z16[(size_t)wid * 64 + lane]) * A + B, 0.f);
  int deg = e1 - e0;
  if (deg > 0) {
    int last = e1 - 1;
    if (deg <= 16) {
#pragma unroll
      for (int i = 0; i < 16; i++) {
        int m = e0 + i;
        int s = csr[min(m, last)];
        float v = fmaxf(bf2f(z16[(size_t)s * 64 + lane]) * A + B, 0.f);
        acc += (m < e1) ? v : 0.f;
      }
    } else {
#pragma unroll
      for (int i = 0; i < 32; i++) {
        int m = e0 + i;
        int s = csr[min(m, last)];
        float v = fmaxf(bf2f(z16[(size_t)s * 64 + lane]) * A + B, 0.f);
        acc += (m < e1) ? v : 0.f;
      }
      for (int e = e0 + 32; e < e1; e += 16) {
#pragma unroll
        for (int i = 0; i < 16; i++) {
          int m = e + i;
          int s = csr[min(m, last)];
          float v = fmaxf(bf2f(z16[(size_t)s * 64 + lane]) * A + B, 0.f);
          acc += (m < e1) ? v : 0.f;
        }
      }
    }
  }
  vout[(size_t)wid * 64 + lane] = f2bf(acc);
}

// MFMA GEMM: 128 rows/block, 4 waves, wave = 32 rows x 64 cols.
// A: bf16 fragments straight from global (BN+ReLU in-register if dobn).
// W: fp32 -> hi/lo bf16 split, staged transposed [n][k] in LDS with
// k-chunk XOR swizzle (conflict-free ds_read_b128). acc fp32 via
// v_mfma_f32_16x16x32_bf16; two MFMAs (hi+lo) per k-step keep W ~fp32.
// Epilogue: bf16 z store + exact fp32 column sum/sumsq -> stats_out.
__global__ __launch_bounds__(256) void k_gemm2(
    const unsigned short* __restrict__ vin, unsigned short* __restrict__ zout,
    const float* __restrict__ W,
    const float* __restrict__ stats_in, const float* __restrict__ gv,
    const float* __restrict__ bev, int dobn,
    float* __restrict__ stats_out, int N) {
  __shared__ __align__(16) unsigned short Whi[64 * 64];
  __shared__ __align__(16) unsigned short Wlo[64 * 64];
  __shared__ float ABs[128];
  __shared__ float red[512];
  int tid = threadIdx.x;
  int n0 = blockIdx.x * 128;
  if (dobn && tid < 64) {
    float inv_n = 1.f / (float)N;
    float mu = stats_in[tid] * inv_n;
    float var = stats_in[64 + tid] * inv_n - mu * mu;
    float A = rsqrtf(var + BN_EPS) * gv[tid];
    ABs[tid] = A;
    ABs[64 + tid] = bev[tid] - mu * A;
  }
  // stage W: hi/lo bf16, transposed [n][k], k-chunk (8 ushort) XOR swizzle
#pragma unroll
  for (int i = 0; i < 16; i++) {
    int g = tid + i * 256;  // [0,4096)
    int k = g >> 6, n = g & 63;
    float w = W[k * 64 + n];
    unsigned short hi = f2bf(w);
    float resid = w - bf2f(hi);
    unsigned short lo = f2bf(resid);
    int kx = (((k >> 3) ^ (n & 7)) << 3) + (k & 7);
    Whi[n * 64 + kx] = hi;
    Wlo[n * 64 + kx] = lo;
  }
  __syncthreads();

  int wv = tid >> 6;
  int lane = tid & 63;
  int c = lane & 15;  // col in 16-tile / row in A m-tile
  int q = lane >> 4;  // k-group
  int wrow = n0 + wv * 32;

  // A fragments: a[mt][kb], row = wrow + mt*16 + c, k = kb*32 + 8q + j
  bf16x8 afrag[2][2];
#pragma unroll
  for (int mt = 0; mt < 2; mt++) {
    int row = wrow + mt * 16 + c;
#pragma unroll
    for (int kb = 0; kb < 2; kb++) {
      int col0 = kb * 32 + q * 8;
      bf16x8 a = {0, 0, 0, 0, 0, 0, 0, 0};
      if (row < N) {
        a = *(const bf16x8*)(vin + (size_t)row * 64 + col0);
        if (dobn) {
#pragma unroll
          for (int j = 0; j < 8; j++) {
            float f = bf2f((unsigned short)a[j]) * ABs[col0 + j] +
                      ABs[64 + col0 + j];
            a[j] = (short)f2bf(fmaxf(f, 0.f));
          }
        }
      }
      afrag[mt][kb] = a;
    }
  }

  f32x4 acc[2][4];
#pragma unroll
  for (int mt = 0; mt < 2; mt++)
#pragma unroll
    for (int nt = 0; nt < 4; nt++)
      acc[mt][nt] = (f32x4){0.f, 0.f, 0.f, 0.f};

#pragma unroll
  for (int nt = 0; nt < 4; nt++) {
    int cn = nt * 16 + c;
#pragma unroll
    for (int kb = 0; kb < 2; kb++) {
      int kchunk = kb * 4 + q;
      int kx = ((kchunk ^ (cn & 7)) << 3);
      bf16x8 bhi = *(const bf16x8*)(Whi + cn * 64 + kx);
      bf16x8 blo = *(const bf16x8*)(Wlo + cn * 64 + kx);
#pragma unroll
      for (int mt = 0; mt < 2; mt++) {
        acc[mt][nt] = __builtin_amdgcn_mfma_f32_16x16x32_bf16(
            afrag[mt][kb], bhi, acc[mt][nt], 0, 0, 0);
        acc[mt][nt] = __builtin_amdgcn_mfma_f32_16x16x32_bf16(
            afrag[mt][kb], blo, acc[mt][nt], 0, 0, 0);
      }
    }
  }

  // store z (bf16): lane holds rows 4q+r, col nt*16+c
#pragma unroll
  for (int mt = 0; mt < 2; mt++) {
#pragma unroll
    for (int r = 0; r < 4; r++) {
      int row = wrow + mt * 16 + q * 4 + r;
      if (row < N) {
        unsigned short* zr = zout + (size_t)row * 64 + c;
        zr[0] = f2bf(acc[mt][0][r]);
        zr[16] = f2bf(acc[mt][1][r]);
        zr[32] = f2bf(acc[mt][2][r]);
        zr[48] = f2bf(acc[mt][3][r]);
      }
    }
  }

  // column sum / sumsq over this block's rows (phantom rows are exact 0)
  float cs[4], cq[4];
#pragma unroll
  for (int nt = 0; nt < 4; nt++) {
    float s = 0.f, s2 = 0.f;
#pragma unroll
    for (int mt = 0; mt < 2; mt++)
#pragma unroll
      for (int r = 0; r < 4; r++) {
        float v = acc[mt][nt][r];
        s += v;
        s2 += v * v;
      }
    s += __shfl_xor(s, 16);
    s += __shfl_xor(s, 32);
    s2 += __shfl_xor(s2, 16);
    s2 += __shfl_xor(s2, 32);
    cs[nt] = s;
    cq[nt] = s2;
  }
  if (lane < 16) {
#pragma unroll
    for (int nt = 0; nt < 4; nt++) {
      red[wv * 128 + nt * 16 + lane] = cs[nt];
      red[wv * 128 + 64 + nt * 16 + lane] = cq[nt];
    }
  }
  __syncthreads();
  if (tid < 64) {
    float a = red[tid] + red[128 + tid] + red[256 + tid] + red[384 + tid];
    float b = red[64 + tid] + red[192 + tid] + red[320 + tid] + red[448 + tid];
    atomicAdd(&stats_out[tid], a);
    atomicAdd(&stats_out[64 + tid], b);
  }
}

// JK heads on MFMA: out[n] = lsm(logits[n] + sum_l relu(bn(z_l[n])) @ fcW_{l+1})
// 128 rows/block, 4 waves, wave = 32 rows x 16 cols (10 real + 6 pad).
// fcW hi/lo bf16 [n][k] swizzled in LDS; acc accumulates across 3 layers.
// log_softmax via 16-lane-group shfl_xor butterflies on the C layout.
__global__ __launch_bounds__(256) void k_head_mfma(
    const unsigned short* __restrict__ z0, const unsigned short* __restrict__ z1,
    const unsigned short* __restrict__ z2, const float* __restrict__ stats,
    const float* __restrict__ gbn, const float* __restrict__ bbn,
    const float* __restrict__ fcW, const float* __restrict__ logits,
    float* __restrict__ out, int N) {
  __shared__ __align__(16) unsigned short Bh[3 * 1024];
  __shared__ __align__(16) unsigned short Bl[3 * 1024];
  __shared__ float ABs[3 * 128];
  int tid = threadIdx.x;
  if (tid < 64) {
    float inv_n = 1.f / (float)N;
#pragma unroll
    for (int l = 0; l < 3; l++) {
      const float* st = stats + (2 * l + 1) * 128;
      float mu = st[tid] * inv_n;
      float var = st[64 + tid] * inv_n - mu * mu;
      float A = rsqrtf(var + BN_EPS) * gbn[l * 64 + tid];
      ABs[l * 128 + tid] = A;
      ABs[l * 128 + 64 + tid] = bbn[l * 64 + tid] - mu * A;
    }
  }
  // stage fcW[l+1] as B[n][k] hi/lo bf16, swizzled k-chunks (pad n>=10 -> 0)
#pragma unroll
  for (int i = 0; i < 12; i++) {
    int g = tid + i * 256;  // [0, 3072)
    int l = g >> 10;
    int rem = g & 1023;
    int n = rem & 15, k = rem >> 4;
    float w = (n < 10) ? fcW[(l + 1) * 640 + k * 10 + n] : 0.f;
    unsigned short hi = f2bf(w);
    float resid = w - bf2f(hi);
    int idx = l * 1024 + n * 64 + (((k >> 3) ^ (n & 7)) << 3) + (k & 7);
    Bh[idx] = hi;
    Bl[idx] = f2bf(resid);
  }
  __syncthreads();

  int wv = tid >> 6, lane = tid & 63;
  int c = lane & 15, q = lane >> 4;
  int wrow = blockIdx.x * 128 + wv * 32;

  f32x4 acc[2];
  acc[0] = (f32x4){0.f, 0.f, 0.f, 0.f};
  acc[1] = (f32x4){0.f, 0.f, 0.f, 0.f};
#pragma unroll
  for (int l = 0; l < 3; l++) {
    const unsigned short* z = (l == 0) ? z0 : (l == 1) ? z1 : z2;
    const float* AB = ABs + l * 128;
#pragma unroll
    for (int kb = 0; kb < 2; kb++) {
      int kchunk = kb * 4 + q;
      int kx = ((kchunk ^ (c & 7)) << 3);
      bf16x8 bh = *(const bf16x8*)(Bh + l * 1024 + c * 64 + kx);
      bf16x8 bl = *(const bf16x8*)(Bl + l * 1024 + c * 64 + kx);
      int col0 = kb * 32 + q * 8;
#pragma unroll
      for (int mt = 0; mt < 2; mt++) {
        int row = wrow + mt * 16 + c;
        bf16x8 a = {0, 0, 0, 0, 0, 0, 0, 0};
        if (row < N) {
          a = *(const bf16x8*)(z + (size_t)row * 64 + col0);
#pragma unroll
          for (int j = 0; j < 8; j++) {
            float f = bf2f((unsigned short)a[j]) * AB[col0 + j] +
                      AB[64 + col0 + j];
            a[j] = (short)f2bf(fmaxf(f, 0.f));
          }
        }
        acc[mt] = __builtin_amdgcn_mfma_f32_16x16x32_bf16(a, bh, acc[mt],
                                                          0, 0, 0);
        acc[mt] = __builtin_amdgcn_mfma_f32_16x16x32_bf16(a, bl, acc[mt],
                                                          0, 0, 0);
      }
    }
  }
  // epilogue: +logits, log_softmax over cols (c<10), write out
#pragma unroll
  for (int mt = 0; mt < 2; mt++) {
    float v[4], vm[4];
#pragma unroll
    for (int r = 0; r < 4; r++) {
      int row = wrow + mt * 16 + q * 4 + r;
      float lg = 0.f;
      if (row < N && c < 10) lg = logits[(size_t)row * 10 + c];
      v[r] = acc[mt][r] + lg;
      vm[r] = (c < 10) ? v[r] : -INFINITY;
    }
#pragma unroll
    for (int off = 1; off < 16; off <<= 1) {
#pragma unroll
      for (int r = 0; r < 4; r++) vm[r] = fmaxf(vm[r], __shfl_xor(vm[r], off));
    }
    float sm[4];
#pragma unroll
    for (int r = 0; r < 4; r++) sm[r] = (c < 10) ? expf(v[r] - vm[r]) : 0.f;
#pragma unroll
    for (int off = 1; off < 16; off <<= 1) {
#pragma unroll
      for (int r = 0; r < 4; r++) sm[r] += __shfl_xor(sm[r], off);
    }
#pragma unroll
    for (int r = 0; r < 4; r++) {
      int row = wrow + mt * 16 + q * 4 + r;
      if (row < N && c < 10)
        out[(size_t)row * 10 + c] = v[r] - (logf(sm[r]) + vm[r]);
    }
  }
}

extern "C" void kernel_launch(void* const* d_in, const int* in_sizes, int n_in,
                              void* d_out, int out_size, void* d_ws, size_t ws_size,
                              hipStream_t stream) {
  const float* x = (const float*)d_in[0];
  const int* ei = (const int*)d_in[1];
  const float* W1 = (const float*)d_in[2];
  const float* g1 = (const float*)d_in[4];
  const float* be1 = (const float*)d_in[5];
  const float* W2 = (const float*)d_in[6];
  const float* gbn = (const float*)d_in[8];
  const float* bbn = (const float*)d_in[9];
  const float* fcW = (const float*)d_in[10];
  const float* fcb = (const float*)d_in[11];
  float* out = (float*)d_out;

  const int N = in_sizes[0] / 64;
  const int E = in_sizes[1] / 2;
  const int* src = ei;
  const int* dst = ei + E;

  char* ws = (char*)d_ws;
  size_t off = 0;
  auto alloc = [&](size_t bytes) -> void* {
    void* p = ws + off;
    off = (off + bytes + 255) & ~(size_t)255;
    return p;
  };
  int* bcur = (int*)alloc(NBKT * 4);          // zeroed by memset node
  float* stats = (float*)alloc(6 * 128 * 4);  // zeroed by bucketsort blk 0
  int* offs = (int*)alloc((size_t)NBKT * 512 * 4);
  int* bend = (int*)alloc(NBKT * 4);
  int* csr = (int*)alloc((size_t)NBKT * BCAP * 4);
  float* logits = (float*)alloc((size_t)N * 10 * 4);
  unsigned short* x16 = (unsigned short*)alloc((size_t)N * 64 * 2);
  unsigned short* v16 = (unsigned short*)alloc((size_t)N * 64 * 2);
  unsigned short* z1_16 = (unsigned short*)alloc((size_t)N * 64 * 2);
  unsigned short* z16a = (unsigned short*)alloc((size_t)N * 64 * 2);
  unsigned short* z16b = (unsigned short*)alloc((size_t)N * 64 * 2);
  unsigned short* z16c = (unsigned short*)alloc((size_t)N * 64 * 2);
  int2* ep = (int2*)alloc((size_t)NBKT * BCAP * 8);
  (void)ws_size;
  (void)n_in;
  (void)out_size;

  unsigned short* z16l[3] = {z16a, z16b, z16c};
  int nb = (N + 255) / 256;
  int gb = (N + 127) / 128;
  int ab = (N * 64 + 255) / 256;
  int nparts = (E + PCHUNK - 1) / PCHUNK;
  hipMemsetAsync(bcur, 0, NBKT * 4, stream);
  k_part_head<<<nparts + nb, 256, 0, stream>>>(src, dst, bcur, ep, E, nparts, x,
                                               fcW, fcb, logits, x16, N);
  k_bucketsort<<<NBKT, 256, 0, stream>>>(ep, bcur, offs, bend, csr, stats);

  for (int l = 0; l < 3; l++) {
    float* st1 = stats + (2 * l) * 128;
    float* st2 = stats + (2 * l + 1) * 128;
    if (l == 0) {
      k_agg<<<ab, 256, 0, stream>>>(x16, offs, bend, csr, v16, N);
    } else {
      float* st2p = stats + (2 * (l - 1) + 1) * 128;
      k_aggbn<<<ab, 256, 0, stream>>>(z16l[l - 1], st2p, gbn + (l - 1) * 64,
                                      bbn + (l - 1) * 64, offs, bend, csr,
                                      v16, N);
    }
    k_gemm2<<<gb, 256, 0, stream>>>(v16, z1_16, W1 + l * 4096, nullptr, nullptr,
                                    nullptr, 0, st1, N);
    k_gemm2<<<gb, 256, 0, stream>>>(z1_16, z16l[l], W2 + l * 4096, st1,
                                    g1 + l * 64, be1 + l * 64, 1, st2, N);
  }
  k_head_mfma<<<gb, 256, 0, stream>>>(z16a, z16b, z16c, stats, gbn, bbn, fcW,
                                      logits, out, N);
}

// Round 4
// 453.381 us; speedup vs baseline: 1.1814x; 1.1814x over previous
//
#include <hip/hip_runtime.h>
#include <math.h>

// GIN: N=100000 nodes, E=1600000 edges, F=D=64, L=3 layers, C=10 classes.
// R17: agg kernels rebuilt as 4-rows-per-instruction gathers with
//   SCALAR indices (fixes R15: no per-lane index loads; fixes R16: no
//   extra full-latency rounds).
//   lane = 16*es + fgrp: es picks 1 of 4 edges (via cndmask on 4 scalar
//   csr values), fgrp covers 4 features as uint2 (8B). One gather instr
//   = 4 complete 128B rows -> E/4 gather instrs instead of E.
//   Tail slots clamp to in-bounds scalars, masked by w=0 (cheap L1 hits).
//   Cross-es reduce via shfl_xor(16/32); es==0 lanes store ushort4.
//   k_head_mfma (R16) and MFMA k_gemm2 (R14) + CSR build unchanged.

#define BN_EPS 1e-5f
#define NBKT 256     // dst buckets (dst>>9)
#define BCAP 12288   // per-bucket edge capacity (mean 8163, +45 sigma)
#define PCHUNK 4096  // edges per partition block

typedef __attribute__((ext_vector_type(8))) short bf16x8;
typedef __attribute__((ext_vector_type(4))) float f32x4;

__device__ __forceinline__ float bf2f(unsigned short u) {
  return __uint_as_float(((unsigned int)u) << 16);
}
__device__ __forceinline__ unsigned short f2bf(float x) {  // RNE
  unsigned int b = __float_as_uint(x);
  return (unsigned short)((b + 0x7FFFu + ((b >> 16) & 1u)) >> 16);
}
__device__ __forceinline__ float bflo(unsigned int u) {
  return __uint_as_float(u << 16);
}
__device__ __forceinline__ float bfhi(unsigned int u) {
  return __uint_as_float(u & 0xffff0000u);
}

// ---------- CSR build ----------

// combined dispatch: blocks [0,nparts) partition edges into fixed-capacity
// dst-buckets (direct atomicAdd on bcur); rest do head_init (+x16 shadow).
__global__ __launch_bounds__(256) void k_part_head(
    const int* __restrict__ src, const int* __restrict__ dst,
    int* __restrict__ bcur, int2* __restrict__ ep, int E, int nparts,
    const float* __restrict__ x, const float* __restrict__ fcW0,
    const float* __restrict__ fcb, float* __restrict__ logits,
    unsigned short* __restrict__ x16, int N) {
  __shared__ char smem[256 * 17 * 4];
  int tid = threadIdx.x;
  if ((int)blockIdx.x < nparts) {
    int* lh = (int*)smem;
    int* lbase = lh + NBKT;
    int* lcur = lh + 2 * NBKT;
    int base = blockIdx.x * PCHUNK;
    int end = min(base + PCHUNK, E);
    lh[tid] = 0;
    lcur[tid] = 0;
    __syncthreads();
    for (int e = base + tid; e < end; e += 256) atomicAdd(&lh[dst[e] >> 9], 1);
    __syncthreads();
    int c = lh[tid];
    lbase[tid] = c ? (tid * BCAP + atomicAdd(&bcur[tid], c)) : 0;
    __syncthreads();
    for (int e = base + tid; e < end; e += 256) {
      int d = dst[e];
      int b = d >> 9;
      int r = atomicAdd(&lcur[b], 1);
      ep[lbase[b] + r] = make_int2(src[e], d);
    }
  } else {
    float* vs = (float*)smem;
    int n0 = (blockIdx.x - nparts) * 256;
    int n = n0 + tid;
    float acc[10];
#pragma unroll
    for (int c = 0; c < 10; c++) acc[c] = 0.f;
#pragma unroll 1
    for (int fb = 0; fb < 64; fb += 16) {
      __syncthreads();
#pragma unroll
      for (int g = 0; g < 4; g++) {
        int r = g * 64 + (tid >> 2);
        int q = tid & 3;
        int rn = n0 + r;
        float4 t = make_float4(0.f, 0.f, 0.f, 0.f);
        if (rn < N) {
          t = *(const float4*)(x + (size_t)rn * 64 + fb + 4 * q);
          *(ushort4*)(x16 + (size_t)rn * 64 + fb + 4 * q) =
              make_ushort4(f2bf(t.x), f2bf(t.y), f2bf(t.z), f2bf(t.w));
        }
        int base = r * 17 + 4 * q;
        vs[base] = t.x;
        vs[base + 1] = t.y;
        vs[base + 2] = t.z;
        vs[base + 3] = t.w;
      }
      __syncthreads();
      for (int fc = 0; fc < 16; fc++) {
        int f = fb + fc;
        float vf = vs[tid * 17 + fc];
        const float* wr = fcW0 + f * 10;
#pragma unroll
        for (int c = 0; c < 10; c++) acc[c] += vf * wr[c];
      }
    }
    if (n < N) {
      float* lr = logits + (size_t)n * 10;
#pragma unroll
      for (int c = 0; c < 10; c++)
        lr[c] = acc[c] + (fcb[c] + fcb[10 + c] + fcb[20 + c] + fcb[30 + c]);
    }
  }
}

// per-bucket LDS counting sort. Emits offs, bend[b], csr. Blk 0 zeroes stats.
__global__ __launch_bounds__(256) void k_bucketsort(
    const int2* __restrict__ ep, const int* __restrict__ bcur,
    int* __restrict__ offs, int* __restrict__ bend, int* __restrict__ csr,
    float* __restrict__ stats) {
  __shared__ int cnt[512];
  __shared__ int ts[256];
  __shared__ int cur[512];
  int t = threadIdx.x;
  int b = blockIdx.x;
  if (b == 0) {
    for (int i = t; i < 768; i += 256) stats[i] = 0.f;
  }
  int lo = b * BCAP;
  int hi = lo + bcur[b];
  cnt[t] = 0;
  cnt[t + 256] = 0;
  __syncthreads();
  for (int e = lo + t; e < hi; e += 256) atomicAdd(&cnt[ep[e].y & 511], 1);
  __syncthreads();
  int c0 = cnt[2 * t], c1 = cnt[2 * t + 1];
  int s = c0 + c1;
  ts[t] = s;
  __syncthreads();
  for (int o = 1; o < 256; o <<= 1) {
    int add = (t >= o) ? ts[t - o] : 0;
    __syncthreads();
    ts[t] += add;
    __syncthreads();
  }
  int excl = ts[t] - s;
  cur[2 * t] = excl;
  cur[2 * t + 1] = excl + c0;
  int n0 = b << 9;
  offs[n0 + 2 * t] = lo + excl;
  offs[n0 + 2 * t + 1] = lo + excl + c0;
  if (t == 255) bend[b] = lo + ts[255];
  __syncthreads();
  for (int e = lo + t; e < hi; e += 256) {
    int2 p = ep[e];
    int pos = atomicAdd(&cur[p.y & 511], 1);
    csr[lo + pos] = p.x;
  }
}

// ---------- compute ----------

// layer-0 aggregation: v16[n] = bf16(x16[n] + sum x16[src])
// wave = 1 node; es = lane>>4 picks edge slot, fgrp = lane&15 covers 4
// features (uint2). Indices stay scalar; lane base via cndmask of 4 scalars.
__global__ __launch_bounds__(256) void k_agg(
    const unsigned short* __restrict__ h16, const int* __restrict__ offs,
    const int* __restrict__ bend, const int* __restrict__ csr,
    unsigned short* __restrict__ vout, int N) {
  int gid = blockIdx.x * blockDim.x + threadIdx.x;
  int wid = __builtin_amdgcn_readfirstlane(gid >> 6);
  if (wid >= N) return;
  int lane = threadIdx.x & 63;
  int es = lane >> 4;
  int fo = (lane & 15) * 4;
  int e0 = offs[wid];
  int e1 = ((wid & 511) == 511) ? bend[wid >> 9] : offs[wid + 1];
  int last = e1 - 1;
  float4 acc;
  {
    uint2 u = *(const uint2*)(h16 + (size_t)wid * 64 + fo);
    float w = (es == 0) ? 1.f : 0.f;
    acc.x = w * bflo(u.x);
    acc.y = w * bfhi(u.x);
    acc.z = w * bflo(u.y);
    acc.w = w * bfhi(u.y);
  }
#pragma unroll 1
  for (int e = e0; e < e1; e += 16) {
#pragma unroll
    for (int g = 0; g < 4; g++) {
      int m = e + g * 4;  // scalar
      int i0 = csr[m];    // scalar loads; reads past bend are masked below
      int i1 = csr[m + 1];
      int i2 = csr[m + 2];
      int i3 = csr[m + 3];
      int idx = (es == 0) ? i0 : (es == 1) ? i1 : (es == 2) ? i2 : i3;
      bool ok = (m + es <= last);
      int s = ok ? idx : wid;
      float w = ok ? 1.f : 0.f;
      uint2 u = *(const uint2*)(h16 + (size_t)s * 64 + fo);
      acc.x += w * bflo(u.x);
      acc.y += w * bfhi(u.x);
      acc.z += w * bflo(u.y);
      acc.w += w * bfhi(u.y);
    }
  }
  acc.x += __shfl_xor(acc.x, 16); acc.x += __shfl_xor(acc.x, 32);
  acc.y += __shfl_xor(acc.y, 16); acc.y += __shfl_xor(acc.y, 32);
  acc.z += __shfl_xor(acc.z, 16); acc.z += __shfl_xor(acc.z, 32);
  acc.w += __shfl_xor(acc.w, 16); acc.w += __shfl_xor(acc.w, 32);
  if (es == 0) {
    *(ushort4*)(vout + (size_t)wid * 64 + fo) =
        make_ushort4(f2bf(acc.x), f2bf(acc.y), f2bf(acc.z), f2bf(acc.w));
  }
}

// BN+ReLU aggregation: v16[n] = bf16(relu(z16[n]*A+B) + sum relu(z16[src]*A+B))
__global__ __launch_bounds__(256) void k_aggbn(
    const unsigned short* __restrict__ z16,
    const float* __restrict__ stats_in, const float* __restrict__ gv,
    const float* __restrict__ bev,
    const int* __restrict__ offs, const int* __restrict__ bend,
    const int* __restrict__ csr, unsigned short* __restrict__ vout, int N) {
  __shared__ float ABs[128];
  int tid = threadIdx.x;
  if (tid < 64) {
    float inv_n = 1.f / (float)N;
    float mu = stats_in[tid] * inv_n;
    float var = stats_in[64 + tid] * inv_n - mu * mu;
    float A = rsqrtf(var + BN_EPS) * gv[tid];
    ABs[tid] = A;
    ABs[64 + tid] = bev[tid] - mu * A;
  }
  __syncthreads();
  int gid = blockIdx.x * blockDim.x + tid;
  int wid = __builtin_amdgcn_readfirstlane(gid >> 6);
  if (wid >= N) return;
  int lane = tid & 63;
  int es = lane >> 4;
  int fo = (lane & 15) * 4;
  float4 A4 = *(const float4*)(ABs + fo);
  float4 B4 = *(const float4*)(ABs + 64 + fo);
  int e0 = offs[wid];
  int e1 = ((wid & 511) == 511) ? bend[wid >> 9] : offs[wid + 1];
  int last = e1 - 1;
  float4 acc;
  {
    uint2 u = *(const uint2*)(z16 + (size_t)wid * 64 + fo);
    float w = (es == 0) ? 1.f : 0.f;
    acc.x = w * fmaxf(bflo(u.x) * A4.x + B4.x, 0.f);
    acc.y = w * fmaxf(bfhi(u.x) * A4.y + B4.y, 0.f);
    acc.z = w * fmaxf(bflo(u.y) * A4.z + B4.z, 0.f);
    acc.w = w * fmaxf(bfhi(u.y) * A4.w + B4.w, 0.f);
  }
#pragma unroll 1
  for (int e = e0; e < e1; e += 16) {
#pragma unroll
    for (int g = 0; g < 4; g++) {
      int m = e + g * 4;
      int i0 = csr[m];
      int i1 = csr[m + 1];
      int i2 = csr[m + 2];
      int i3 = csr[m + 3];
      int idx = (es == 0) ? i0 : (es == 1) ? i1 : (es == 2) ? i2 : i3;
      bool ok = (m + es <= last);
      int s = ok ? idx : wid;
      float w = ok ? 1.f : 0.f;
      uint2 u = *(const uint2*)(z16 + (size_t)s * 64 + fo);
      acc.x += w * fmaxf(bflo(u.x) * A4.x + B4.x, 0.f);
      acc.y += w * fmaxf(bfhi(u.x) * A4.y + B4.y, 0.f);
      acc.z += w * fmaxf(bflo(u.y) * A4.z + B4.z, 0.f);
      acc.w += w * fmaxf(bfhi(u.y) * A4.w + B4.w, 0.f);
    }
  }
  acc.x += __shfl_xor(acc.x, 16); acc.x += __shfl_xor(acc.x, 32);
  acc.y += __shfl_xor(acc.y, 16); acc.y += __shfl_xor(acc.y, 32);
  acc.z += __shfl_xor(acc.z, 16); acc.z += __shfl_xor(acc.z, 32);
  acc.w += __shfl_xor(acc.w, 16); acc.w += __shfl_xor(acc.w, 32);
  if (es == 0) {
    *(ushort4*)(vout + (size_t)wid * 64 + fo) =
        make_ushort4(f2bf(acc.x), f2bf(acc.y), f2bf(acc.z), f2bf(acc.w));
  }
}

// MFMA GEMM: 128 rows/block, 4 waves, wave = 32 rows x 64 cols.
// A: bf16 fragments straight from global (BN+ReLU in-register if dobn).
// W: fp32 -> hi/lo bf16 split, staged transposed [n][k] in LDS with
// k-chunk XOR swizzle (conflict-free ds_read_b128). acc fp32 via
// v_mfma_f32_16x16x32_bf16; two MFMAs (hi+lo) per k-step keep W ~fp32.
// Epilogue: bf16 z store + exact fp32 column sum/sumsq -> stats_out.
__global__ __launch_bounds__(256) void k_gemm2(
    const unsigned short* __restrict__ vin, unsigned short* __restrict__ zout,
    const float* __restrict__ W,
    const float* __restrict__ stats_in, const float* __restrict__ gv,
    const float* __restrict__ bev, int dobn,
    float* __restrict__ stats_out, int N) {
  __shared__ __align__(16) unsigned short Whi[64 * 64];
  __shared__ __align__(16) unsigned short Wlo[64 * 64];
  __shared__ float ABs[128];
  __shared__ float red[512];
  int tid = threadIdx.x;
  int n0 = blockIdx.x * 128;
  if (dobn && tid < 64) {
    float inv_n = 1.f / (float)N;
    float mu = stats_in[tid] * inv_n;
    float var = stats_in[64 + tid] * inv_n - mu * mu;
    float A = rsqrtf(var + BN_EPS) * gv[tid];
    ABs[tid] = A;
    ABs[64 + tid] = bev[tid] - mu * A;
  }
  // stage W: hi/lo bf16, transposed [n][k], k-chunk (8 ushort) XOR swizzle
#pragma unroll
  for (int i = 0; i < 16; i++) {
    int g = tid + i * 256;  // [0,4096)
    int k = g >> 6, n = g & 63;
    float w = W[k * 64 + n];
    unsigned short hi = f2bf(w);
    float resid = w - bf2f(hi);
    unsigned short lo = f2bf(resid);
    int kx = (((k >> 3) ^ (n & 7)) << 3) + (k & 7);
    Whi[n * 64 + kx] = hi;
    Wlo[n * 64 + kx] = lo;
  }
  __syncthreads();

  int wv = tid >> 6;
  int lane = tid & 63;
  int c = lane & 15;  // col in 16-tile / row in A m-tile
  int q = lane >> 4;  // k-group
  int wrow = n0 + wv * 32;

  // A fragments: a[mt][kb], row = wrow + mt*16 + c, k = kb*32 + 8q + j
  bf16x8 afrag[2][2];
#pragma unroll
  for (int mt = 0; mt < 2; mt++) {
    int row = wrow + mt * 16 + c;
#pragma unroll
    for (int kb = 0; kb < 2; kb++) {
      int col0 = kb * 32 + q * 8;
      bf16x8 a = {0, 0, 0, 0, 0, 0, 0, 0};
      if (row < N) {
        a = *(const bf16x8*)(vin + (size_t)row * 64 + col0);
        if (dobn) {
#pragma unroll
          for (int j = 0; j < 8; j++) {
            float f = bf2f((unsigned short)a[j]) * ABs[col0 + j] +
                      ABs[64 + col0 + j];
            a[j] = (short)f2bf(fmaxf(f, 0.f));
          }
        }
      }
      afrag[mt][kb] = a;
    }
  }

  f32x4 acc[2][4];
#pragma unroll
  for (int mt = 0; mt < 2; mt++)
#pragma unroll
    for (int nt = 0; nt < 4; nt++)
      acc[mt][nt] = (f32x4){0.f, 0.f, 0.f, 0.f};

#pragma unroll
  for (int nt = 0; nt < 4; nt++) {
    int cn = nt * 16 + c;
#pragma unroll
    for (int kb = 0; kb < 2; kb++) {
      int kchunk = kb * 4 + q;
      int kx = ((kchunk ^ (cn & 7)) << 3);
      bf16x8 bhi = *(const bf16x8*)(Whi + cn * 64 + kx);
      bf16x8 blo = *(const bf16x8*)(Wlo + cn * 64 + kx);
#pragma unroll
      for (int mt = 0; mt < 2; mt++) {
        acc[mt][nt] = __builtin_amdgcn_mfma_f32_16x16x32_bf16(
            afrag[mt][kb], bhi, acc[mt][nt], 0, 0, 0);
        acc[mt][nt] = __builtin_amdgcn_mfma_f32_16x16x32_bf16(
            afrag[mt][kb], blo, acc[mt][nt], 0, 0, 0);
      }
    }
  }

  // store z (bf16): lane holds rows 4q+r, col nt*16+c
#pragma unroll
  for (int mt = 0; mt < 2; mt++) {
#pragma unroll
    for (int r = 0; r < 4; r++) {
      int row = wrow + mt * 16 + q * 4 + r;
      if (row < N) {
        unsigned short* zr = zout + (size_t)row * 64 + c;
        zr[0] = f2bf(acc[mt][0][r]);
        zr[16] = f2bf(acc[mt][1][r]);
        zr[32] = f2bf(acc[mt][2][r]);
        zr[48] = f2bf(acc[mt][3][r]);
      }
    }
  }

  // column sum / sumsq over this block's rows (phantom rows are exact 0)
  float cs[4], cq[4];
#pragma unroll
  for (int nt = 0; nt < 4; nt++) {
    float s = 0.f, s2 = 0.f;
#pragma unroll
    for (int mt = 0; mt < 2; mt++)
#pragma unroll
      for (int r = 0; r < 4; r++) {
        float v = acc[mt][nt][r];
        s += v;
        s2 += v * v;
      }
    s += __shfl_xor(s, 16);
    s += __shfl_xor(s, 32);
    s2 += __shfl_xor(s2, 16);
    s2 += __shfl_xor(s2, 32);
    cs[nt] = s;
    cq[nt] = s2;
  }
  if (lane < 16) {
#pragma unroll
    for (int nt = 0; nt < 4; nt++) {
      red[wv * 128 + nt * 16 + lane] = cs[nt];
      red[wv * 128 + 64 + nt * 16 + lane] = cq[nt];
    }
  }
  __syncthreads();
  if (tid < 64) {
    float a = red[tid] + red[128 + tid] + red[256 + tid] + red[384 + tid];
    float b = red[64 + tid] + red[192 + tid] + red[320 + tid] + red[448 + tid];
    atomicAdd(&stats_out[tid], a);
    atomicAdd(&stats_out[64 + tid], b);
  }
}

// JK heads on MFMA: out[n] = lsm(logits[n] + sum_l relu(bn(z_l[n])) @ fcW_{l+1})
// 128 rows/block, 4 waves, wave = 32 rows x 16 cols (10 real + 6 pad).
// fcW hi/lo bf16 [n][k] swizzled in LDS; acc accumulates across 3 layers.
// log_softmax via 16-lane-group shfl_xor butterflies on the C layout.
__global__ __launch_bounds__(256) void k_head_mfma(
    const unsigned short* __restrict__ z0, const unsigned short* __restrict__ z1,
    const unsigned short* __restrict__ z2, const float* __restrict__ stats,
    const float* __restrict__ gbn, const float* __restrict__ bbn,
    const float* __restrict__ fcW, const float* __restrict__ logits,
    float* __restrict__ out, int N) {
  __shared__ __align__(16) unsigned short Bh[3 * 1024];
  __shared__ __align__(16) unsigned short Bl[3 * 1024];
  __shared__ float ABs[3 * 128];
  int tid = threadIdx.x;
  if (tid < 64) {
    float inv_n = 1.f / (float)N;
#pragma unroll
    for (int l = 0; l < 3; l++) {
      const float* st = stats + (2 * l + 1) * 128;
      float mu = st[tid] * inv_n;
      float var = st[64 + tid] * inv_n - mu * mu;
      float A = rsqrtf(var + BN_EPS) * gbn[l * 64 + tid];
      ABs[l * 128 + tid] = A;
      ABs[l * 128 + 64 + tid] = bbn[l * 64 + tid] - mu * A;
    }
  }
  // stage fcW[l+1] as B[n][k] hi/lo bf16, swizzled k-chunks (pad n>=10 -> 0)
#pragma unroll
  for (int i = 0; i < 12; i++) {
    int g = tid + i * 256;  // [0, 3072)
    int l = g >> 10;
    int rem = g & 1023;
    int n = rem & 15, k = rem >> 4;
    float w = (n < 10) ? fcW[(l + 1) * 640 + k * 10 + n] : 0.f;
    unsigned short hi = f2bf(w);
    float resid = w - bf2f(hi);
    int idx = l * 1024 + n * 64 + (((k >> 3) ^ (n & 7)) << 3) + (k & 7);
    Bh[idx] = hi;
    Bl[idx] = f2bf(resid);
  }
  __syncthreads();

  int wv = tid >> 6, lane = tid & 63;
  int c = lane & 15, q = lane >> 4;
  int wrow = blockIdx.x * 128 + wv * 32;

  f32x4 acc[2];
  acc[0] = (f32x4){0.f, 0.f, 0.f, 0.f};
  acc[1] = (f32x4){0.f, 0.f, 0.f, 0.f};
#pragma unroll
  for (int l = 0; l < 3; l++) {
    const unsigned short* z = (l == 0) ? z0 : (l == 1) ? z1 : z2;
    const float* AB = ABs + l * 128;
#pragma unroll
    for (int kb = 0; kb < 2; kb++) {
      int kchunk = kb * 4 + q;
      int kx = ((kchunk ^ (c & 7)) << 3);
      bf16x8 bh = *(const bf16x8*)(Bh + l * 1024 + c * 64 + kx);
      bf16x8 bl = *(const bf16x8*)(Bl + l * 1024 + c * 64 + kx);
      int col0 = kb * 32 + q * 8;
#pragma unroll
      for (int mt = 0; mt < 2; mt++) {
        int row = wrow + mt * 16 + c;
        bf16x8 a = {0, 0, 0, 0, 0, 0, 0, 0};
        if (row < N) {
          a = *(const bf16x8*)(z + (size_t)row * 64 + col0);
#pragma unroll
          for (int j = 0; j < 8; j++) {
            float f = bf2f((unsigned short)a[j]) * AB[col0 + j] +
                      AB[64 + col0 + j];
            a[j] = (short)f2bf(fmaxf(f, 0.f));
          }
        }
        acc[mt] = __builtin_amdgcn_mfma_f32_16x16x32_bf16(a, bh, acc[mt],
                                                          0, 0, 0);
        acc[mt] = __builtin_amdgcn_mfma_f32_16x16x32_bf16(a, bl, acc[mt],
                                                          0, 0, 0);
      }
    }
  }
  // epilogue: +logits, log_softmax over cols (c<10), write out
#pragma unroll
  for (int mt = 0; mt < 2; mt++) {
    float v[4], vm[4];
#pragma unroll
    for (int r = 0; r < 4; r++) {
      int row = wrow + mt * 16 + q * 4 + r;
      float lg = 0.f;
      if (row < N && c < 10) lg = logits[(size_t)row * 10 + c];
      v[r] = acc[mt][r] + lg;
      vm[r] = (c < 10) ? v[r] : -INFINITY;
    }
#pragma unroll
    for (int off = 1; off < 16; off <<= 1) {
#pragma unroll
      for (int r = 0; r < 4; r++) vm[r] = fmaxf(vm[r], __shfl_xor(vm[r], off));
    }
    float sm[4];
#pragma unroll
    for (int r = 0; r < 4; r++) sm[r] = (c < 10) ? expf(v[r] - vm[r]) : 0.f;
#pragma unroll
    for (int off = 1; off < 16; off <<= 1) {
#pragma unroll
      for (int r = 0; r < 4; r++) sm[r] += __shfl_xor(sm[r], off);
    }
#pragma unroll
    for (int r = 0; r < 4; r++) {
      int row = wrow + mt * 16 + q * 4 + r;
      if (row < N && c < 10)
        out[(size_t)row * 10 + c] = v[r] - (logf(sm[r]) + vm[r]);
    }
  }
}

extern "C" void kernel_launch(void* const* d_in, const int* in_sizes, int n_in,
                              void* d_out, int out_size, void* d_ws, size_t ws_size,
                              hipStream_t stream) {
  const float* x = (const float*)d_in[0];
  const int* ei = (const int*)d_in[1];
  const float* W1 = (const float*)d_in[2];
  const float* g1 = (const float*)d_in[4];
  const float* be1 = (const float*)d_in[5];
  const float* W2 = (const float*)d_in[6];
  const float* gbn = (const float*)d_in[8];
  const float* bbn = (const float*)d_in[9];
  const float* fcW = (const float*)d_in[10];
  const float* fcb = (const float*)d_in[11];
  float* out = (float*)d_out;

  const int N = in_sizes[0] / 64;
  const int E = in_sizes[1] / 2;
  const int* src = ei;
  const int* dst = ei + E;

  char* ws = (char*)d_ws;
  size_t off = 0;
  auto alloc = [&](size_t bytes) -> void* {
    void* p = ws + off;
    off = (off + bytes + 255) & ~(size_t)255;
    return p;
  };
  int* bcur = (int*)alloc(NBKT * 4);          // zeroed by memset node
  float* stats = (float*)alloc(6 * 128 * 4);  // zeroed by bucketsort blk 0
  int* offs = (int*)alloc((size_t)NBKT * 512 * 4);
  int* bend = (int*)alloc(NBKT * 4);
  int* csr = (int*)alloc((size_t)NBKT * BCAP * 4);
  float* logits = (float*)alloc((size_t)N * 10 * 4);
  unsigned short* x16 = (unsigned short*)alloc((size_t)N * 64 * 2);
  unsigned short* v16 = (unsigned short*)alloc((size_t)N * 64 * 2);
  unsigned short* z1_16 = (unsigned short*)alloc((size_t)N * 64 * 2);
  unsigned short* z16a = (unsigned short*)alloc((size_t)N * 64 * 2);
  unsigned short* z16b = (unsigned short*)alloc((size_t)N * 64 * 2);
  unsigned short* z16c = (unsigned short*)alloc((size_t)N * 64 * 2);
  int2* ep = (int2*)alloc((size_t)NBKT * BCAP * 8);
  (void)ws_size;
  (void)n_in;
  (void)out_size;

  unsigned short* z16l[3] = {z16a, z16b, z16c};
  int nb = (N + 255) / 256;
  int gb = (N + 127) / 128;
  int ab = (N * 64 + 255) / 256;
  int nparts = (E + PCHUNK - 1) / PCHUNK;
  hipMemsetAsync(bcur, 0, NBKT * 4, stream);
  k_part_head<<<nparts + nb, 256, 0, stream>>>(src, dst, bcur, ep, E, nparts, x,
                                               fcW, fcb, logits, x16, N);
  k_bucketsort<<<NBKT, 256, 0, stream>>>(ep, bcur, offs, bend, csr, stats);

  for (int l = 0; l < 3; l++) {
    float* st1 = stats + (2 * l) * 128;
    float* st2 = stats + (2 * l + 1) * 128;
    if (l == 0) {
      k_agg<<<ab, 256, 0, stream>>>(x16, offs, bend, csr, v16, N);
    } else {
      float* st2p = stats + (2 * (l - 1) + 1) * 128;
      k_aggbn<<<ab, 256, 0, stream>>>(z16l[l - 1], st2p, gbn + (l - 1) * 64,
                                      bbn + (l - 1) * 64, offs, bend, csr,
                                      v16, N);
    }
    k_gemm2<<<gb, 256, 0, stream>>>(v16, z1_16, W1 + l * 4096, nullptr, nullptr,
                                    nullptr, 0, st1, N);
    k_gemm2<<<gb, 256, 0, stream>>>(z1_16, z16l[l], W2 + l * 4096, st1,
                                    g1 + l * 64, be1 + l * 64, 1, st2, N);
  }
  k_head_mfma<<<gb, 256, 0, stream>>>(z16a, z16b, z16c, stats, gbn, bbn, fcW,
                                      logits, out, N);
}